// Round 10
// baseline (415.421 us; speedup 1.0000x reference)
//
#include <hip/hip_runtime.h>
#include <stdint.h>

#define NROWS 8192
#define DIM 128
#define MARGIN 0.5f

typedef short short8 __attribute__((ext_vector_type(8)));   // 8 bf16 (4 VGPRs)
typedef float f32x4 __attribute__((ext_vector_type(4)));
typedef int   int4v __attribute__((ext_vector_type(4)));

static __device__ __forceinline__ unsigned short f2bf(float f) {
    union { float f; unsigned u; } x; x.f = f;
    unsigned u = x.u;
    return (unsigned short)((u + 0x7FFFu + ((u >> 16) & 1u)) >> 16);  // RNE
}
static __device__ __forceinline__ unsigned fbits(float f) {
    union { float f; unsigned u; } x; x.f = f; return x.u;
}

// ---------------------------------------------------------------------------
// prep: build the FRAGMENT-ORDERED bf16 matrix
//   dst = efrag + (row>>4)*4096 + (d>>4)*1024 + (((d>>2)&3)*16 + (row&15))*16
//         + (d&3)*4          (d = lane, handles cols 2d,2d+1)
// so every MFMA A/B fragment load in mine is ONE coalesced dwordx4:
//   frag(tile,ks) = efrag + tile*4096 + ks*1024 + lane*16.
// Also c_j = sq_j + 512 (f32 exact), pos/neg atomic init, out[0]=0.
// ---------------------------------------------------------------------------
__global__ __launch_bounds__(256) void prep(const float* __restrict__ emb,
                                            char* __restrict__ efrag,
                                            float* __restrict__ cbuf,
                                            unsigned* __restrict__ pos,
                                            unsigned* __restrict__ neg,
                                            float* __restrict__ out) {
    const int d = threadIdx.x & 63;
    const int row = blockIdx.x * 4 + (threadIdx.x >> 6);
    const float2 v = reinterpret_cast<const float2*>(emb + row * DIM)[d];
    float sq = v.x * v.x + v.y * v.y;
#pragma unroll
    for (int m = 1; m < 64; m <<= 1) sq += __shfl_xor(sq, m, 64);
    const unsigned pack = ((unsigned)f2bf(v.y) << 16) | (unsigned)f2bf(v.x);
    char* dst = efrag + (size_t)(row >> 4) * 4096 + (d >> 4) * 1024
              + ((((d >> 2) & 3) * 16 + (row & 15)) * 16) + (d & 3) * 4;
    *reinterpret_cast<unsigned*>(dst) = pack;
    if (d == 0) cbuf[row] = sq + 512.0f;
    if (d == 1) pos[row] = 0u;
    if (d == 2) neg[row] = 0xFFFFFFFFu;
    if (blockIdx.x == 0 && threadIdx.x == 0) out[0] = 0.0f;
}

// ---------------------------------------------------------------------------
// mine: fused Gram-GEMM + batch-hard mining. NO LDS, NO barriers.
// Grid: 32 i-blocks (256 rows) x 32 j-chunks (256 cols) = 1024 blocks
// (4 blocks/CU, co-resident). Block: 4 waves; wave owns FOUR 16-row i-tiles
// (bfrag in regs). All 4 waves share the j-chunk -> af re-reads L1-hit.
// T14 pipeline: the jt-loop is fully unrolled; tile t+1's gating operands
// {cinit', af0'..af3'} are ISSUED before tile t's MFMA cluster, so their
// ~200cy L1/L2 latency hides under t's 16 MFMA + selects instead of sitting
// on the per-tile critical path (this was the round-7 stall).
// Score s = dot - c_j/2 < 0:
//   hardest positive = max d2 -> MAX u32 bits ; hardest negative -> MIN u32.
// Candidate = (s_bits & ~8191) | j (v_and_or_b32). Publish via
// atomicMax(pos[i]) / atomicMin(neg[i]) — 8192 distinct addresses.
// ---------------------------------------------------------------------------
__global__ __launch_bounds__(256, 4) void mine(const char* __restrict__ efrag,
                                               const float* __restrict__ cbuf,
                                               const int* __restrict__ labels,
                                               unsigned* __restrict__ pos,
                                               unsigned* __restrict__ neg) {
    const int tid  = threadIdx.x;
    const int wave = tid >> 6;
    const int lane = tid & 63;
    const int l15  = lane & 15;
    const int lhi  = lane >> 4;
    const int iblk = blockIdx.x & 31;
    const int cblk = blockIdx.x >> 5;
    const int ibase = iblk * 256 + wave * 64;

    // B operand (i side): 4 tiles, coalesced fragment loads, regs all kernel.
    short8 bfrag[4][4];
    int labi[4];
#pragma unroll
    for (int it = 0; it < 4; ++it) {
        const char* bt = efrag + (size_t)((ibase >> 4) + it) * 4096 + lane * 16;
#pragma unroll
        for (int ks = 0; ks < 4; ++ks)
            bfrag[it][ks] = *reinterpret_cast<const short8*>(bt + ks * 1024);
        labi[it] = labels[ibase + it * 16 + l15];
    }

    unsigned bp[4] = {0u, 0u, 0u, 0u};
    unsigned bn[4] = {0xFFFFFFFFu, 0xFFFFFFFFu, 0xFFFFFFFFu, 0xFFFFFFFFu};

    const int jc = cblk * 256;
    const char* aj = efrag + (size_t)(cblk * 16) * 4096 + lane * 16;

    // Tile-0 preload (gating operands).
    f32x4 cin_c = *reinterpret_cast<const f32x4*>(cbuf + jc + lhi * 4) * -0.5f;
    short8 af0_c = *reinterpret_cast<const short8*>(aj);
    short8 af1_c = *reinterpret_cast<const short8*>(aj + 1024);
    short8 af2_c = *reinterpret_cast<const short8*>(aj + 2048);
    short8 af3_c = *reinterpret_cast<const short8*>(aj + 3072);

#pragma unroll
    for (int jt = 0; jt < 16; ++jt) {
        const int jb = jc + jt * 16;
        const char* atn = aj + (size_t)(jt + 1) * 4096;

        // Issue next tile's gating loads FIRST (jt=15 over-reads into the
        // adjacent ws scratch region — valid memory, result unused).
        const f32x4 cin_n = *reinterpret_cast<const f32x4*>(cbuf + jb + 16 + lhi * 4) * -0.5f;
        const short8 af0_n = *reinterpret_cast<const short8*>(atn);
        const short8 af1_n = *reinterpret_cast<const short8*>(atn + 1024);
        const short8 af2_n = *reinterpret_cast<const short8*>(atn + 2048);
        const short8 af3_n = *reinterpret_cast<const short8*>(atn + 3072);
        const int4v labj = *reinterpret_cast<const int4v*>(labels + jb + lhi * 4);

        f32x4 acc[4];
#pragma unroll
        for (int it = 0; it < 4; ++it)
            acc[it] = __builtin_amdgcn_mfma_f32_16x16x32_bf16(af0_c, bfrag[it][0], cin_c, 0, 0, 0);
#pragma unroll
        for (int it = 0; it < 4; ++it)
            acc[it] = __builtin_amdgcn_mfma_f32_16x16x32_bf16(af1_c, bfrag[it][1], acc[it], 0, 0, 0);
#pragma unroll
        for (int it = 0; it < 4; ++it)
            acc[it] = __builtin_amdgcn_mfma_f32_16x16x32_bf16(af2_c, bfrag[it][2], acc[it], 0, 0, 0);
#pragma unroll
        for (int it = 0; it < 4; ++it)
            acc[it] = __builtin_amdgcn_mfma_f32_16x16x32_bf16(af3_c, bfrag[it][3], acc[it], 0, 0, 0);

        const int jv = jb + lhi * 4;        // this lane's j for r=0 (then +r)
#pragma unroll
        for (int it = 0; it < 4; ++it) {
#pragma unroll
            for (int r = 0; r < 4; ++r) {
                const unsigned cand = (fbits(acc[it][r]) & 0xFFFFE000u) | (unsigned)(jv + r);
                const bool eq = (labj[r] == labi[it]);
                const unsigned psel = eq ? cand : 0u;            // vcc cndmask
                const unsigned nsel = eq ? 0xFFFFFFFFu : cand;   // vcc cndmask
                bp[it] = bp[it] > psel ? bp[it] : psel;
                bn[it] = bn[it] < nsel ? bn[it] : nsel;
            }
        }

        // Rotate pipeline registers (SSA rename under full unroll).
        cin_c = cin_n;
        af0_c = af0_n; af1_c = af1_n; af2_c = af2_n; af3_c = af3_n;
    }

    // cross-lane: lanes {l, l^16, l^32, l^48} share the same i (= l15)
#pragma unroll
    for (int it = 0; it < 4; ++it) {
        unsigned o;
        o = (unsigned)__shfl_xor((int)bp[it], 16, 64); bp[it] = bp[it] > o ? bp[it] : o;
        o = (unsigned)__shfl_xor((int)bp[it], 32, 64); bp[it] = bp[it] > o ? bp[it] : o;
        o = (unsigned)__shfl_xor((int)bn[it], 16, 64); bn[it] = bn[it] < o ? bn[it] : o;
        o = (unsigned)__shfl_xor((int)bn[it], 32, 64); bn[it] = bn[it] < o ? bn[it] : o;
        if (lane < 16) {
            const int i = ibase + it * 16 + lane;
            atomicMax(&pos[i], bp[it]);
            atomicMin(&neg[i], bn[it]);
        }
    }
}

// ---------------------------------------------------------------------------
// lossk (fin fused): 512 blocks x 4 waves; each wave handles 4 rows.
// Uniform read of mined indices, exact f32 ap/an, butterfly sum, one scaled
// atomicAdd per block into out[0] (512 atomics total).
// ---------------------------------------------------------------------------
__global__ __launch_bounds__(256) void lossk(const float* __restrict__ emb,
                                             const unsigned* __restrict__ pos,
                                             const unsigned* __restrict__ neg,
                                             float* __restrict__ out) {
    __shared__ float wsum[4];
    const int tid = threadIdx.x, lane = tid & 63, wave = tid >> 6;
    float accw = 0.f;
#pragma unroll
    for (int k = 0; k < 4; ++k) {
        const int i = blockIdx.x * 16 + wave * 4 + k;      // 0..8191
        const int jp = (int)(pos[i] & 8191u);
        const int jn = (int)(neg[i] & 8191u);
        const float2 a = reinterpret_cast<const float2*>(emb + (size_t)i  * DIM)[lane];
        const float2 b = reinterpret_cast<const float2*>(emb + (size_t)jp * DIM)[lane];
        const float2 c = reinterpret_cast<const float2*>(emb + (size_t)jn * DIM)[lane];
        float dx = a.x - b.x, dy = a.y - b.y;
        const float ap = dx * dx + dy * dy;
        dx = a.x - c.x; dy = a.y - c.y;
        const float an = dx * dx + dy * dy;
        float s = ap - an;
#pragma unroll
        for (int m = 1; m < 64; m <<= 1) s += __shfl_xor(s, m, 64);
        if (lane == 0) accw += fmaxf(s + MARGIN, 0.f);
    }
    if (lane == 0) wsum[wave] = accw;
    __syncthreads();
    if (tid == 0)
        atomicAdd(out, (wsum[0] + wsum[1] + wsum[2] + wsum[3]) * (1.0f / (float)NROWS));
}

// ---------------------------------------------------------------------------
extern "C" void kernel_launch(void* const* d_in, const int* in_sizes, int n_in,
                              void* d_out, int out_size, void* d_ws, size_t ws_size,
                              hipStream_t stream) {
    const float* emb   = (const float*)d_in[0];
    const int* labels  = (const int*)d_in[1];
    float* out = (float*)d_out;
    char* ws = (char*)d_ws;

    char*     efrag = ws;                                   // 2 MB
    float*    cbuf  = (float*)   (ws + (size_t)2097152);    // 32 KB
    unsigned* pos   = (unsigned*)(ws + (size_t)2129920);    // 32 KB
    unsigned* neg   = (unsigned*)(ws + (size_t)2162688);    // 32 KB

    prep <<<2048, 256, 0, stream>>>(emb, efrag, cbuf, pos, neg, out);
    mine <<<1024, 256, 0, stream>>>(efrag, cbuf, labels, pos, neg);
    lossk<<<512, 256, 0, stream>>>(emb, pos, neg, out);
}

// Round 11
// 96.495 us; speedup vs baseline: 4.3051x; 4.3051x over previous
//
#include <hip/hip_runtime.h>
#include <stdint.h>

#define NROWS 8192
#define DIM 128
#define MARGIN 0.5f

typedef short short8 __attribute__((ext_vector_type(8)));   // 8 bf16 (4 VGPRs)
typedef float f32x4 __attribute__((ext_vector_type(4)));
typedef int   int4v __attribute__((ext_vector_type(4)));

static __device__ __forceinline__ unsigned short f2bf(float f) {
    union { float f; unsigned u; } x; x.f = f;
    unsigned u = x.u;
    return (unsigned short)((u + 0x7FFFu + ((u >> 16) & 1u)) >> 16);  // RNE
}
static __device__ __forceinline__ unsigned fbits(float f) {
    union { float f; unsigned u; } x; x.f = f; return x.u;
}

// ---------------------------------------------------------------------------
// prep: build the FRAGMENT-ORDERED bf16 matrix
//   dst = efrag + (row>>4)*4096 + (d>>4)*1024 + (((d>>2)&3)*16 + (row&15))*16
//         + (d&3)*4          (d = lane, handles cols 2d,2d+1)
// so every MFMA A/B fragment load in mine is ONE coalesced dwordx4:
//   frag(tile,ks) = efrag + tile*4096 + ks*1024 + lane*16.
// Also c_j = sq_j + 512 (f32 exact), pos/neg atomic init, out[0]=0.
// ---------------------------------------------------------------------------
__global__ __launch_bounds__(256) void prep(const float* __restrict__ emb,
                                            char* __restrict__ efrag,
                                            float* __restrict__ cbuf,
                                            unsigned* __restrict__ pos,
                                            unsigned* __restrict__ neg,
                                            float* __restrict__ out) {
    const int d = threadIdx.x & 63;
    const int row = blockIdx.x * 4 + (threadIdx.x >> 6);
    const float2 v = reinterpret_cast<const float2*>(emb + row * DIM)[d];
    float sq = v.x * v.x + v.y * v.y;
#pragma unroll
    for (int m = 1; m < 64; m <<= 1) sq += __shfl_xor(sq, m, 64);
    const unsigned pack = ((unsigned)f2bf(v.y) << 16) | (unsigned)f2bf(v.x);
    char* dst = efrag + (size_t)(row >> 4) * 4096 + (d >> 4) * 1024
              + ((((d >> 2) & 3) * 16 + (row & 15)) * 16) + (d & 3) * 4;
    *reinterpret_cast<unsigned*>(dst) = pack;
    if (d == 0) cbuf[row] = sq + 512.0f;
    if (d == 1) pos[row] = 0u;
    if (d == 2) neg[row] = 0xFFFFFFFFu;
    if (blockIdx.x == 0 && threadIdx.x == 0) out[0] = 0.0f;
}

// ---------------------------------------------------------------------------
// mine: fused Gram-GEMM + batch-hard mining. NO LDS, NO barriers.
// Grid: 64 i-blocks (128 rows) x 32 j-chunks (256 cols) = 2048 blocks
// (8 blocks/CU of work). Block: 4 waves; wave owns TWO 16-row i-tiles
// (bfrag in regs, ~90 VGPR total). __launch_bounds__(256,5): cap 102 VGPR,
// ~5 waves/SIMD resident drawn from >=2 DIFFERENT blocks at different
// phases -> per-tile vmcnt stalls de-correlate across waves (the R1..R8
// structures all had lockstep waves whose load-waits coincided).
// R7-proven body: per j-tile loads issued in two halves inside the loop
// (small live ranges, no spill), all operands via coalesced dwordx4.
// Score s = dot - c_j/2 < 0:
//   hardest positive = max d2 -> MAX u32 bits ; hardest negative -> MIN u32.
// Candidate = (s_bits & ~8191) | j (v_and_or_b32). Publish via
// atomicMax(pos[i]) / atomicMin(neg[i]) — 8192 distinct addresses.
// ---------------------------------------------------------------------------
__global__ __launch_bounds__(256, 5) void mine(const char* __restrict__ efrag,
                                               const float* __restrict__ cbuf,
                                               const int* __restrict__ labels,
                                               unsigned* __restrict__ pos,
                                               unsigned* __restrict__ neg) {
    const int tid  = threadIdx.x;
    const int wave = tid >> 6;
    const int lane = tid & 63;
    const int l15  = lane & 15;
    const int lhi  = lane >> 4;
    const int iblk = blockIdx.x & 63;
    const int cblk = blockIdx.x >> 6;
    const int ibase = iblk * 128 + wave * 32;

    // B operand (i side): 2 tiles, coalesced fragment loads, regs all kernel.
    short8 bfrag[2][4];
    int labi[2];
#pragma unroll
    for (int it = 0; it < 2; ++it) {
        const char* bt = efrag + (size_t)((ibase >> 4) + it) * 4096 + lane * 16;
#pragma unroll
        for (int ks = 0; ks < 4; ++ks)
            bfrag[it][ks] = *reinterpret_cast<const short8*>(bt + ks * 1024);
        labi[it] = labels[ibase + it * 16 + l15];
    }

    unsigned bp[2] = {0u, 0u};
    unsigned bn[2] = {0xFFFFFFFFu, 0xFFFFFFFFu};

    const int jc = cblk * 256;
    const char* aj = efrag + (size_t)(cblk * 16) * 4096 + lane * 16;

#pragma unroll 2
    for (int jt = 0; jt < 16; ++jt) {
        const int jb = jc + jt * 16;
        const int4v labj = *reinterpret_cast<const int4v*>(labels + jb + lhi * 4);
        const f32x4 cinit = *reinterpret_cast<const f32x4*>(cbuf + jb + lhi * 4) * -0.5f;
        const char* at = aj + (size_t)jt * 4096;

        // ks in two halves to cap af register pressure (R7-proven).
        const short8 af0 = *reinterpret_cast<const short8*>(at);
        const short8 af1 = *reinterpret_cast<const short8*>(at + 1024);
        f32x4 acc[2];
#pragma unroll
        for (int it = 0; it < 2; ++it)
            acc[it] = __builtin_amdgcn_mfma_f32_16x16x32_bf16(af0, bfrag[it][0], cinit, 0, 0, 0);
#pragma unroll
        for (int it = 0; it < 2; ++it)
            acc[it] = __builtin_amdgcn_mfma_f32_16x16x32_bf16(af1, bfrag[it][1], acc[it], 0, 0, 0);
        const short8 af2 = *reinterpret_cast<const short8*>(at + 2048);
        const short8 af3 = *reinterpret_cast<const short8*>(at + 3072);
#pragma unroll
        for (int it = 0; it < 2; ++it)
            acc[it] = __builtin_amdgcn_mfma_f32_16x16x32_bf16(af2, bfrag[it][2], acc[it], 0, 0, 0);
#pragma unroll
        for (int it = 0; it < 2; ++it)
            acc[it] = __builtin_amdgcn_mfma_f32_16x16x32_bf16(af3, bfrag[it][3], acc[it], 0, 0, 0);

        const int jv = jb + lhi * 4;        // this lane's j for r=0 (then +r)
#pragma unroll
        for (int it = 0; it < 2; ++it) {
#pragma unroll
            for (int r = 0; r < 4; ++r) {
                const unsigned cand = (fbits(acc[it][r]) & 0xFFFFE000u) | (unsigned)(jv + r);
                const bool eq = (labj[r] == labi[it]);
                const unsigned psel = eq ? cand : 0u;            // vcc cndmask
                const unsigned nsel = eq ? 0xFFFFFFFFu : cand;   // vcc cndmask
                bp[it] = bp[it] > psel ? bp[it] : psel;
                bn[it] = bn[it] < nsel ? bn[it] : nsel;
            }
        }
    }

    // cross-lane: lanes {l, l^16, l^32, l^48} share the same i (= l15)
#pragma unroll
    for (int it = 0; it < 2; ++it) {
        unsigned o;
        o = (unsigned)__shfl_xor((int)bp[it], 16, 64); bp[it] = bp[it] > o ? bp[it] : o;
        o = (unsigned)__shfl_xor((int)bp[it], 32, 64); bp[it] = bp[it] > o ? bp[it] : o;
        o = (unsigned)__shfl_xor((int)bn[it], 16, 64); bn[it] = bn[it] < o ? bn[it] : o;
        o = (unsigned)__shfl_xor((int)bn[it], 32, 64); bn[it] = bn[it] < o ? bn[it] : o;
    }
    if (lane < 32) {   // lanes 0-15 publish it=0 (i=ibase+lane); 16-31 it=1
        const int it = lane >> 4;
        const int i = ibase + lane;   // == ibase + it*16 + (lane&15)
        atomicMax(&pos[i], bp[it]);
        atomicMin(&neg[i], bn[it]);
    }
}

// ---------------------------------------------------------------------------
// lossk (fin fused): 512 blocks x 4 waves; each wave handles 4 rows.
// Uniform read of mined indices, exact f32 ap/an, butterfly sum, one scaled
// atomicAdd per block into out[0] (512 atomics total). Validated in R10.
// ---------------------------------------------------------------------------
__global__ __launch_bounds__(256) void lossk(const float* __restrict__ emb,
                                             const unsigned* __restrict__ pos,
                                             const unsigned* __restrict__ neg,
                                             float* __restrict__ out) {
    __shared__ float wsum[4];
    const int tid = threadIdx.x, lane = tid & 63, wave = tid >> 6;
    float accw = 0.f;
#pragma unroll
    for (int k = 0; k < 4; ++k) {
        const int i = blockIdx.x * 16 + wave * 4 + k;      // 0..8191
        const int jp = (int)(pos[i] & 8191u);
        const int jn = (int)(neg[i] & 8191u);
        const float2 a = reinterpret_cast<const float2*>(emb + (size_t)i  * DIM)[lane];
        const float2 b = reinterpret_cast<const float2*>(emb + (size_t)jp * DIM)[lane];
        const float2 c = reinterpret_cast<const float2*>(emb + (size_t)jn * DIM)[lane];
        float dx = a.x - b.x, dy = a.y - b.y;
        const float ap = dx * dx + dy * dy;
        dx = a.x - c.x; dy = a.y - c.y;
        const float an = dx * dx + dy * dy;
        float s = ap - an;
#pragma unroll
        for (int m = 1; m < 64; m <<= 1) s += __shfl_xor(s, m, 64);
        if (lane == 0) accw += fmaxf(s + MARGIN, 0.f);
    }
    if (lane == 0) wsum[wave] = accw;
    __syncthreads();
    if (tid == 0)
        atomicAdd(out, (wsum[0] + wsum[1] + wsum[2] + wsum[3]) * (1.0f / (float)NROWS));
}

// ---------------------------------------------------------------------------
extern "C" void kernel_launch(void* const* d_in, const int* in_sizes, int n_in,
                              void* d_out, int out_size, void* d_ws, size_t ws_size,
                              hipStream_t stream) {
    const float* emb   = (const float*)d_in[0];
    const int* labels  = (const int*)d_in[1];
    float* out = (float*)d_out;
    char* ws = (char*)d_ws;

    char*     efrag = ws;                                   // 2 MB
    float*    cbuf  = (float*)   (ws + (size_t)2097152);    // 32 KB
    unsigned* pos   = (unsigned*)(ws + (size_t)2129920);    // 32 KB
    unsigned* neg   = (unsigned*)(ws + (size_t)2162688);    // 32 KB

    prep <<<2048, 256, 0, stream>>>(emb, efrag, cbuf, pos, neg, out);
    mine <<<2048, 256, 0, stream>>>(efrag, cbuf, labels, pos, neg);
    lossk<<<512, 256, 0, stream>>>(emb, pos, neg, out);
}

// Round 12
// 94.465 us; speedup vs baseline: 4.3976x; 1.0215x over previous
//
#include <hip/hip_runtime.h>
#include <stdint.h>

#define NROWS 8192
#define DIM 128
#define MARGIN 0.5f

typedef short short8 __attribute__((ext_vector_type(8)));   // 8 bf16 (4 VGPRs)
typedef float f32x4 __attribute__((ext_vector_type(4)));
typedef int   int4v __attribute__((ext_vector_type(4)));

#define GLDS16(g, l) __builtin_amdgcn_global_load_lds( \
    (const __attribute__((address_space(1))) unsigned int*)(g), \
    (__attribute__((address_space(3))) unsigned int*)(l), 16, 0, 0)

static __device__ __forceinline__ unsigned short f2bf(float f) {
    union { float f; unsigned u; } x; x.f = f;
    unsigned u = x.u;
    return (unsigned short)((u + 0x7FFFu + ((u >> 16) & 1u)) >> 16);  // RNE
}
static __device__ __forceinline__ unsigned fbits(float f) {
    union { float f; unsigned u; } x; x.f = f; return x.u;
}

// ---------------------------------------------------------------------------
// prep: build the FRAGMENT-ORDERED bf16 matrix
//   dst = efrag + (row>>4)*4096 + (d>>4)*1024 + (((d>>2)&3)*16 + (row&15))*16
//         + (d&3)*4          (d = lane, handles cols 2d,2d+1)
// frag(tile,ks) = efrag + tile*4096 + ks*1024 + lane*16  (one coalesced
// dwordx4 per fragment, and LINEAR for global_load_lds staging).
// Also c_j = sq_j + 512 (f32 exact), pos/neg atomic init, out[0]=0.
// ---------------------------------------------------------------------------
__global__ __launch_bounds__(256) void prep(const float* __restrict__ emb,
                                            char* __restrict__ efrag,
                                            float* __restrict__ cbuf,
                                            unsigned* __restrict__ pos,
                                            unsigned* __restrict__ neg,
                                            float* __restrict__ out) {
    const int d = threadIdx.x & 63;
    const int row = blockIdx.x * 4 + (threadIdx.x >> 6);
    const float2 v = reinterpret_cast<const float2*>(emb + row * DIM)[d];
    float sq = v.x * v.x + v.y * v.y;
#pragma unroll
    for (int m = 1; m < 64; m <<= 1) sq += __shfl_xor(sq, m, 64);
    const unsigned pack = ((unsigned)f2bf(v.y) << 16) | (unsigned)f2bf(v.x);
    char* dst = efrag + (size_t)(row >> 4) * 4096 + (d >> 4) * 1024
              + ((((d >> 2) & 3) * 16 + (row & 15)) * 16) + (d & 3) * 4;
    *reinterpret_cast<unsigned*>(dst) = pack;
    if (d == 0) cbuf[row] = sq + 512.0f;
    if (d == 1) pos[row] = 0u;
    if (d == 2) neg[row] = 0xFFFFFFFFu;
    if (blockIdx.x == 0 && threadIdx.x == 0) out[0] = 0.0f;
}

// ---------------------------------------------------------------------------
// mine: fused Gram-GEMM + batch-hard mining with a T3+T4 counted-vmcnt
// 2-buffer LDS pipeline (loads stay in flight ACROSS barriers — no vmcnt(0)
// drain in the main loop; this is the mechanism every prior round lacked).
// Grid: 32 i-blocks (256 rows) x 32 j-chunks (256 cols) = 1024 blocks.
// Block: 4 waves; wave owns FOUR 16-row i-tiles (bfrag in regs).
// j-chunk = 8 stages x 32 j-rows (8KB, fragment-ordered, LINEAR copy).
// STAGE: wave w, call q stages 1KB sub-block (q*4+w) — dest = uniform base
// + lane*16, exactly the global_load_lds HW pattern (rule #21 safe, no
// swizzle needed: ds_read af = lane*16 within 1KB, conflict-free).
// Per iter: STAGE(t+1) -> vmcnt(2) [stage t landed, t+1 in flight] ->
// s_barrier -> compute(buf t) -> s_barrier [buffer-reuse protection].
// Score s = dot - c_j/2 < 0:  hardest positive = MAX u32, negative = MIN.
// Candidate = (s_bits & ~8191) | j. Publish atomicMax(pos)/atomicMin(neg).
// ---------------------------------------------------------------------------
__global__ __launch_bounds__(256) void mine(const char* __restrict__ efrag,
                                            const float* __restrict__ cbuf,
                                            const int* __restrict__ labels,
                                            unsigned* __restrict__ pos,
                                            unsigned* __restrict__ neg) {
    __shared__ __align__(16) char smem[2][8192];
    const int tid  = threadIdx.x;
    const int wave = tid >> 6;
    const int lane = tid & 63;
    const int l15  = lane & 15;
    const int lhi  = lane >> 4;
    const int iblk = blockIdx.x & 31;
    const int cblk = blockIdx.x >> 5;
    const int ibase = iblk * 256 + wave * 64;
    const int jc = cblk * 256;
    const char* jsrc = efrag + (size_t)(cblk * 16) * 4096;  // this chunk: 64KB

    const int sub0 = wave * 1024 + lane * 16;          // call q=0 sub-block
    const int sub1 = (4 + wave) * 1024 + lane * 16;    // call q=1 sub-block

#define STAGE(s, b) do { \
        const char* _s = jsrc + (size_t)(s) * 8192; \
        GLDS16(_s + sub0, &smem[b][sub0]); \
        GLDS16(_s + sub1, &smem[b][sub1]); \
    } while (0)

    STAGE(0, 0);   // prologue stage (in flight during bfrag loads)

    // B operand (i side): 4 tiles, coalesced fragment loads, regs all kernel.
    short8 bfrag[4][4];
    int labi[4];
#pragma unroll
    for (int it = 0; it < 4; ++it) {
        const char* bt = efrag + (size_t)((ibase >> 4) + it) * 4096 + lane * 16;
#pragma unroll
        for (int ks = 0; ks < 4; ++ks)
            bfrag[it][ks] = *reinterpret_cast<const short8*>(bt + ks * 1024);
        labi[it] = labels[ibase + it * 16 + l15];
    }

    unsigned bp[4] = {0u, 0u, 0u, 0u};
    unsigned bn[4] = {0xFFFFFFFFu, 0xFFFFFFFFu, 0xFFFFFFFFu, 0xFFFFFFFFu};

    // Compute one 2-tile stage from LDS buffer `buf`.
    auto compute = [&](const char* buf, int s) {
#pragma unroll
        for (int tt = 0; tt < 2; ++tt) {
            const int jb = jc + s * 32 + tt * 16;
            const int4v labj = *reinterpret_cast<const int4v*>(labels + jb + lhi * 4);
            const f32x4 cinit = *reinterpret_cast<const f32x4*>(cbuf + jb + lhi * 4) * -0.5f;
            const char* at = buf + tt * 4096 + lane * 16;

            const short8 af0 = *reinterpret_cast<const short8*>(at);
            const short8 af1 = *reinterpret_cast<const short8*>(at + 1024);
            f32x4 acc[4];
#pragma unroll
            for (int it = 0; it < 4; ++it)
                acc[it] = __builtin_amdgcn_mfma_f32_16x16x32_bf16(af0, bfrag[it][0], cinit, 0, 0, 0);
#pragma unroll
            for (int it = 0; it < 4; ++it)
                acc[it] = __builtin_amdgcn_mfma_f32_16x16x32_bf16(af1, bfrag[it][1], acc[it], 0, 0, 0);
            const short8 af2 = *reinterpret_cast<const short8*>(at + 2048);
            const short8 af3 = *reinterpret_cast<const short8*>(at + 3072);
#pragma unroll
            for (int it = 0; it < 4; ++it)
                acc[it] = __builtin_amdgcn_mfma_f32_16x16x32_bf16(af2, bfrag[it][2], acc[it], 0, 0, 0);
#pragma unroll
            for (int it = 0; it < 4; ++it)
                acc[it] = __builtin_amdgcn_mfma_f32_16x16x32_bf16(af3, bfrag[it][3], acc[it], 0, 0, 0);

            const int jv = jb + lhi * 4;
#pragma unroll
            for (int it = 0; it < 4; ++it) {
#pragma unroll
                for (int r = 0; r < 4; ++r) {
                    const unsigned cand = (fbits(acc[it][r]) & 0xFFFFE000u) | (unsigned)(jv + r);
                    const bool eq = (labj[r] == labi[it]);
                    const unsigned psel = eq ? cand : 0u;            // vcc cndmask
                    const unsigned nsel = eq ? 0xFFFFFFFFu : cand;   // vcc cndmask
                    bp[it] = bp[it] > psel ? bp[it] : psel;
                    bn[it] = bn[it] < nsel ? bn[it] : nsel;
                }
            }
        }
    };

    // Main pipeline: counted vmcnt, raw barriers, no drain.
    for (int t = 0; t < 7; ++t) {
        STAGE(t + 1, (t + 1) & 1);
        asm volatile("s_waitcnt vmcnt(2)" ::: "memory");  // stage t landed
        __builtin_amdgcn_s_barrier();                      // all waves agree
        compute(smem[t & 1], t);
        __builtin_amdgcn_s_barrier();                      // reads done
    }
    asm volatile("s_waitcnt vmcnt(0)" ::: "memory");       // tail stage landed
    __builtin_amdgcn_s_barrier();
    compute(smem[1], 7);

    // cross-lane: lanes {l, l^16, l^32, l^48} share the same i (= l15)
#pragma unroll
    for (int it = 0; it < 4; ++it) {
        unsigned o;
        o = (unsigned)__shfl_xor((int)bp[it], 16, 64); bp[it] = bp[it] > o ? bp[it] : o;
        o = (unsigned)__shfl_xor((int)bp[it], 32, 64); bp[it] = bp[it] > o ? bp[it] : o;
        o = (unsigned)__shfl_xor((int)bn[it], 16, 64); bn[it] = bn[it] < o ? bn[it] : o;
        o = (unsigned)__shfl_xor((int)bn[it], 32, 64); bn[it] = bn[it] < o ? bn[it] : o;
        if (lane < 16) {
            const int i = ibase + it * 16 + lane;
            atomicMax(&pos[i], bp[it]);
            atomicMin(&neg[i], bn[it]);
        }
    }
#undef STAGE
}

// ---------------------------------------------------------------------------
// lossk (fin fused): 512 blocks x 4 waves; each wave handles 4 rows.
// Uniform read of mined indices, exact f32 ap/an, butterfly sum, one scaled
// atomicAdd per block into out[0] (512 atomics total). Validated R10/R11.
// ---------------------------------------------------------------------------
__global__ __launch_bounds__(256) void lossk(const float* __restrict__ emb,
                                             const unsigned* __restrict__ pos,
                                             const unsigned* __restrict__ neg,
                                             float* __restrict__ out) {
    __shared__ float wsum[4];
    const int tid = threadIdx.x, lane = tid & 63, wave = tid >> 6;
    float accw = 0.f;
#pragma unroll
    for (int k = 0; k < 4; ++k) {
        const int i = blockIdx.x * 16 + wave * 4 + k;      // 0..8191
        const int jp = (int)(pos[i] & 8191u);
        const int jn = (int)(neg[i] & 8191u);
        const float2 a = reinterpret_cast<const float2*>(emb + (size_t)i  * DIM)[lane];
        const float2 b = reinterpret_cast<const float2*>(emb + (size_t)jp * DIM)[lane];
        const float2 c = reinterpret_cast<const float2*>(emb + (size_t)jn * DIM)[lane];
        float dx = a.x - b.x, dy = a.y - b.y;
        const float ap = dx * dx + dy * dy;
        dx = a.x - c.x; dy = a.y - c.y;
        const float an = dx * dx + dy * dy;
        float s = ap - an;
#pragma unroll
        for (int m = 1; m < 64; m <<= 1) s += __shfl_xor(s, m, 64);
        if (lane == 0) accw += fmaxf(s + MARGIN, 0.f);
    }
    if (lane == 0) wsum[wave] = accw;
    __syncthreads();
    if (tid == 0)
        atomicAdd(out, (wsum[0] + wsum[1] + wsum[2] + wsum[3]) * (1.0f / (float)NROWS));
}

// ---------------------------------------------------------------------------
extern "C" void kernel_launch(void* const* d_in, const int* in_sizes, int n_in,
                              void* d_out, int out_size, void* d_ws, size_t ws_size,
                              hipStream_t stream) {
    const float* emb   = (const float*)d_in[0];
    const int* labels  = (const int*)d_in[1];
    float* out = (float*)d_out;
    char* ws = (char*)d_ws;

    char*     efrag = ws;                                   // 2 MB
    float*    cbuf  = (float*)   (ws + (size_t)2097152);    // 32 KB
    unsigned* pos   = (unsigned*)(ws + (size_t)2129920);    // 32 KB
    unsigned* neg   = (unsigned*)(ws + (size_t)2162688);    // 32 KB

    prep <<<2048, 256, 0, stream>>>(emb, efrag, cbuf, pos, neg, out);
    mine <<<1024, 256, 0, stream>>>(efrag, cbuf, labels, pos, neg);
    lossk<<<512, 256, 0, stream>>>(emb, pos, neg, out);
}